// Round 2
// baseline (95.152 us; speedup 1.0000x reference)
//
#include <hip/hip_runtime.h>
#include <math.h>

#define TDIM 512
#define KDIM 8
#define DDIM 8
#define BDIM 2048

#define PSTRIDE 48   // per tk: 8 i-blocks [lin_i, S'_ii, 2S'_ij...] (44), const@44, pad3
#define XSTRIDE 68   // x staging row stride

#define COEF_FLOATS (TDIM * KDIM * PSTRIDE)   // 4096 * 48 = 196608
#define COEF_BYTES  (COEF_FLOATS * 4)         // 786432

#ifndef __has_builtin
#define __has_builtin(x) 0
#endif
#if __has_builtin(__builtin_amdgcn_exp2f)
#define FAST_EXP2(x) __builtin_amdgcn_exp2f(x)
#else
#define FAST_EXP2(x) exp2f(x)
#endif

// ---------------------------------------------------------------------------
// Kernel 1: coefficient builder (Phase A), run ONCE over T*K instead of 8x.
// 256 blocks x 128 thr: each block = 2 t (16 tk x 8 rows).
// 8-lane-parallel f32 Gauss-Jordan Cayley (in-place, inverse accumulates
// through pivot COLUMN), then S = Q diag(0.7213*e^-lv) Q^T folded into
// quadratic-form coefs, written to global ws [4096][48].
// ---------------------------------------------------------------------------
__global__ __launch_bounds__(128) void pecd_coef(
    const float* __restrict__ centers,   // [T,K,8]
    const float* __restrict__ wlogits,   // [T,K]
    const float* __restrict__ logvar,    // [T,K,8]
    const float* __restrict__ covp,      // [T,K,28]
    float* __restrict__ coef)            // [T*K,48] ws
{
    const int tidx = (int)threadIdx.x;
    const int t0   = (int)blockIdx.x * 2;

    const int tk = tidx >> 3;             // 0..15 = (t_local, k)
    const int r  = tidx & 7;
    const size_t tkg = (size_t)(t0 + (tk >> 3)) * 8 + (tk & 7);

    // row r of M = I + A ; A = 0.5*(UT^T - UT), UT strict-upper from
    // flat(n) = v[n] (n<28) | v[55-n] (28<=n<56), n = 8*min+max.
    const float* cb = covp + tkg * 28;
    float row[8];
    #pragma unroll
    for (int j = 0; j < 8; j++) {
        const int lo = (r < j) ? r : j;
        const int hi = (r < j) ? j : r;
        const int n  = 8 * lo + hi;
        const int m  = (r == j) ? 0 : ((n < 28) ? n : 55 - n);
        const float v = cb[m];
        const float a = (r < j) ? -0.5f * v : 0.5f * v;
        row[j] = (r == j) ? 1.0f : a;
    }

    #pragma unroll
    for (int c = 0; c < 8; c++) {
        float prow[8];
        #pragma unroll
        for (int j = 0; j < 8; j++) prow[j] = __shfl(row[j], c, 8);
        const float pinv = 1.0f / prow[c];
        const float f = row[c];
        #pragma unroll
        for (int j = 0; j < 8; j++) {
            if (j == c) {
                row[j] = (r == c) ? pinv : -f * pinv;
            } else {
                const float spiv = prow[j] * pinv;
                row[j] = (r == c) ? spiv : fmaf(-f, spiv, row[j]);
            }
        }
    }
    float qr[8];
    #pragma unroll
    for (int j = 0; j < 8; j++) qr[j] = 2.0f * row[j] - (r == j ? 1.0f : 0.0f);

    const float* lvp = logvar + tkg * 8;
    float sc2[8];
    float sumlv = 0.0f;
    #pragma unroll
    for (int j = 0; j < 8; j++) {
        const float lv = fminf(fmaxf(lvp[j], -3.5f), 3.5f);
        sumlv += lv;
        sc2[j] = 0.7213475204444817f * exp2f(lv * -1.4426950408889634f);
    }
    float w[8];
    #pragma unroll
    for (int j = 0; j < 8; j++) w[j] = qr[j] * sc2[j];

    float Srow[8];
    #pragma unroll
    for (int m = 0; m < 8; m++) {
        float s = 0.0f;
        #pragma unroll
        for (int j = 0; j < 8; j++) s = fmaf(w[j], __shfl(qr[j], m, 8), s);
        Srow[m] = s;
    }

    const float* cp = centers + tkg * 8;
    float tr = 0.0f;
    #pragma unroll
    for (int m = 0; m < 8; m++) tr = fmaf(Srow[m], cp[m], tr);
    const float lin = -2.0f * tr;
    float cpart = cp[r] * tr;
    cpart += __shfl_xor(cpart, 1, 8);
    cpart += __shfl_xor(cpart, 2, 8);
    cpart += __shfl_xor(cpart, 4, 8);   // = c^T S c

    // softmax over k (k = tid bits 3..5, within-wave) -> log2(w)
    float l = fminf(fmaxf(wlogits[tkg], -3.5f), 3.5f);
    float mx = l;
    mx = fmaxf(mx, __shfl_xor(mx, 8, 64));
    mx = fmaxf(mx, __shfl_xor(mx, 16, 64));
    mx = fmaxf(mx, __shfl_xor(mx, 32, 64));
    const float e = exp2f((l - mx) * 1.4426950408889634f);
    float ss = e;
    ss += __shfl_xor(ss, 8, 64);
    ss += __shfl_xor(ss, 16, 64);
    ss += __shfl_xor(ss, 32, 64);
    const float log2w = (l - mx) * 1.4426950408889634f - log2f(ss);
    const float slc = log2w - 10.605984517349169f - 0.7213475204444817f * sumlv;

    float* pp = coef + tkg * PSTRIDE;
    const int o = 9 * r - (r * (r - 1)) / 2;   // 0,9,17,24,30,35,39,42
    pp[o] = lin;
    #pragma unroll
    for (int j = 0; j < 8; j++) {
        if (j >= r) pp[o + 1 + j - r] = Srow[j] * ((j == r) ? 1.0f : 2.0f);
    }
    if (r == 0) pp[44] = cpart - slc;
}

// ---------------------------------------------------------------------------
// Kernel 2: evaluation (Phase B). 2 outputs/thread, grid (64,16) = 1024
// blocks -> 4 blocks/CU x 8 waves = 32 waves/CU (full occupancy).
// wave<->t, lane<->b, 2-b register blocking; x staged coalesced via LDS.
// Coefs are WAVE-UNIFORM: read via readfirstlane-uniform pointer straight
// from global (L2-resident) so the compiler emits s_load into SGPRs —
// removes 360 ds_read_b32/thread from the hot loop (the LDS-issue floor),
// scalar pipe runs in parallel with VALU. Coalesced stores via LDS
// transpose.
// ---------------------------------------------------------------------------
__global__ __launch_bounds__(512, 8) void pecd_main(
    const float* __restrict__ x,         // [B,T,8]
    const float* __restrict__ coef,      // [T*K,48] ws
    float* __restrict__ out)             // [B,T]
{
    __shared__ float xs[64 * XSTRIDE];   // 17.4 KB staging; reused as out buffer

    const int tidx = (int)threadIdx.x;
    const int t0   = (int)blockIdx.x * 8;     // wave w handles t0+w
    const int b0   = (int)blockIdx.y * 128;   // 2 chunks of 64 b

    const int wv = tidx >> 6;
    const int ln = tidx & 63;

    // stage 2 chunks of x coalesced; keep 2 b-rows per lane in registers
    float xv[2][8];
    #pragma unroll
    for (int c = 0; c < 2; c++) {
        if (c) __syncthreads();   // protect xs reuse between chunks
        #pragma unroll
        for (int it = 0; it < 2; it++) {
            const int idx = tidx + it * 512;    // 0..1023 float4s
            const int row = idx >> 4;           // b-row 0..63
            const int col = idx & 15;
            const float4 v =
                *((const float4*)(x + ((size_t)(b0 + c * 64 + row) * TDIM + t0) * DDIM) + col);
            *(float4*)(xs + row * XSTRIDE + col * 4) = v;
        }
        __syncthreads();
        const float* xr = xs + ln * XSTRIDE + wv * 8;
        const float4 a0 = *(const float4*)(xr);
        const float4 a1 = *(const float4*)(xr + 4);
        xv[c][0] = a0.x; xv[c][1] = a0.y; xv[c][2] = a0.z; xv[c][3] = a0.w;
        xv[c][4] = a1.x; xv[c][5] = a1.y; xv[c][6] = a1.z; xv[c][7] = a1.w;
    }

    // wave-uniform coef base -> scalar loads (s_load) from L2-resident ws
    const int wvu = __builtin_amdgcn_readfirstlane(wv);
    const float* __restrict__ pkb = coef + (size_t)(t0 + wvu) * (KDIM * PSTRIDE);

    float acc[2] = {0.f, 0.f};
    #pragma unroll 2
    for (int k = 0; k < KDIM; k++) {
        const float* __restrict__ pk = pkb + k * PSTRIDE;  // uniform address
        const float cst = pk[44];
        float ee[2] = {cst, cst};
        #pragma unroll
        for (int i = 0; i < 8; i++) {
            const int o = 9 * i - (i * (i - 1)) / 2;
            const float lin = pk[o];
            float inner[2] = {lin, lin};
            #pragma unroll
            for (int j = i; j < 8; j++) {
                const float cf = pk[o + 1 + j - i];
                #pragma unroll
                for (int c = 0; c < 2; c++) inner[c] = fmaf(cf, xv[c][j], inner[c]);
            }
            #pragma unroll
            for (int c = 0; c < 2; c++) ee[c] = fmaf(xv[c][i], inner[c], ee[c]);
        }
        #pragma unroll
        for (int c = 0; c < 2; c++) acc[c] += FAST_EXP2(-ee[c]);
    }

    // ---- transpose through LDS (reuse xs: 128 rows x 9 = 4.6 KB) ----
    __syncthreads();   // all xs staging reads done
    #pragma unroll
    for (int c = 0; c < 2; c++)
        xs[(c * 64 + ln) * 9 + wv] = acc[c];   // stride 9: conflict-free
    __syncthreads();
    if (tidx < 256) {
        const int row  = tidx >> 1;    // 0..127 local b
        const int part = tidx & 1;     // float4 half of the 8-t row
        float4 v;
        v.x = xs[row * 9 + part * 4 + 0];
        v.y = xs[row * 9 + part * 4 + 1];
        v.z = xs[row * 9 + part * 4 + 2];
        v.w = xs[row * 9 + part * 4 + 3];
        *(float4*)(out + (size_t)(b0 + row) * TDIM + t0 + part * 4) = v;
    }
}

// ---------------------------------------------------------------------------
// Fallback: original fused single-kernel path (used if ws too small).
// ---------------------------------------------------------------------------
__global__ __launch_bounds__(512, 4) void pecd_fused(
    const float* __restrict__ x,
    const float* __restrict__ centers,
    const float* __restrict__ wlogits,
    const float* __restrict__ logvar,
    const float* __restrict__ covp,
    float* __restrict__ out)
{
    __shared__ float prm[64 * PSTRIDE];
    __shared__ float xs[64 * XSTRIDE];

    const int tidx = (int)threadIdx.x;
    const int t0   = (int)blockIdx.x * 8;
    const int b0   = (int)blockIdx.y * 256;

    {
        const int tk = tidx >> 3;
        const int r  = tidx & 7;
        const size_t tkg = (size_t)(t0 + (tk >> 3)) * 8 + (tk & 7);

        const float* cb = covp + tkg * 28;
        float row[8];
        #pragma unroll
        for (int j = 0; j < 8; j++) {
            const int lo = (r < j) ? r : j;
            const int hi = (r < j) ? j : r;
            const int n  = 8 * lo + hi;
            const int m  = (r == j) ? 0 : ((n < 28) ? n : 55 - n);
            const float v = cb[m];
            const float a = (r < j) ? -0.5f * v : 0.5f * v;
            row[j] = (r == j) ? 1.0f : a;
        }

        #pragma unroll
        for (int c = 0; c < 8; c++) {
            float prow[8];
            #pragma unroll
            for (int j = 0; j < 8; j++) prow[j] = __shfl(row[j], c, 8);
            const float pinv = 1.0f / prow[c];
            const float f = row[c];
            #pragma unroll
            for (int j = 0; j < 8; j++) {
                if (j == c) {
                    row[j] = (r == c) ? pinv : -f * pinv;
                } else {
                    const float spiv = prow[j] * pinv;
                    row[j] = (r == c) ? spiv : fmaf(-f, spiv, row[j]);
                }
            }
        }
        float qr[8];
        #pragma unroll
        for (int j = 0; j < 8; j++) qr[j] = 2.0f * row[j] - (r == j ? 1.0f : 0.0f);

        const float* lvp = logvar + tkg * 8;
        float sc2[8];
        float sumlv = 0.0f;
        #pragma unroll
        for (int j = 0; j < 8; j++) {
            const float lv = fminf(fmaxf(lvp[j], -3.5f), 3.5f);
            sumlv += lv;
            sc2[j] = 0.7213475204444817f * exp2f(lv * -1.4426950408889634f);
        }
        float w[8];
        #pragma unroll
        for (int j = 0; j < 8; j++) w[j] = qr[j] * sc2[j];

        float Srow[8];
        #pragma unroll
        for (int m = 0; m < 8; m++) {
            float s = 0.0f;
            #pragma unroll
            for (int j = 0; j < 8; j++) s = fmaf(w[j], __shfl(qr[j], m, 8), s);
            Srow[m] = s;
        }

        const float* cp = centers + tkg * 8;
        float tr = 0.0f;
        #pragma unroll
        for (int m = 0; m < 8; m++) tr = fmaf(Srow[m], cp[m], tr);
        const float lin = -2.0f * tr;
        float cpart = cp[r] * tr;
        cpart += __shfl_xor(cpart, 1, 8);
        cpart += __shfl_xor(cpart, 2, 8);
        cpart += __shfl_xor(cpart, 4, 8);

        float l = fminf(fmaxf(wlogits[tkg], -3.5f), 3.5f);
        float mx = l;
        mx = fmaxf(mx, __shfl_xor(mx, 8, 64));
        mx = fmaxf(mx, __shfl_xor(mx, 16, 64));
        mx = fmaxf(mx, __shfl_xor(mx, 32, 64));
        const float e = exp2f((l - mx) * 1.4426950408889634f);
        float ss = e;
        ss += __shfl_xor(ss, 8, 64);
        ss += __shfl_xor(ss, 16, 64);
        ss += __shfl_xor(ss, 32, 64);
        const float log2w = (l - mx) * 1.4426950408889634f - log2f(ss);
        const float slc = log2w - 10.605984517349169f - 0.7213475204444817f * sumlv;

        float* pp = prm + tk * PSTRIDE;
        const int o = 9 * r - (r * (r - 1)) / 2;
        pp[o] = lin;
        #pragma unroll
        for (int j = 0; j < 8; j++) {
            if (j >= r) pp[o + 1 + j - r] = Srow[j] * ((j == r) ? 1.0f : 2.0f);
        }
        if (r == 0) pp[44] = cpart - slc;
    }

    const int wv = tidx >> 6;
    const int ln = tidx & 63;

    float xv[4][8];
    #pragma unroll
    for (int c = 0; c < 4; c++) {
        __syncthreads();
        #pragma unroll
        for (int it = 0; it < 2; it++) {
            const int idx = tidx + it * 512;
            const int row = idx >> 4;
            const int col = idx & 15;
            const float4 v =
                *((const float4*)(x + ((size_t)(b0 + c * 64 + row) * TDIM + t0) * DDIM) + col);
            *(float4*)(xs + row * XSTRIDE + col * 4) = v;
        }
        __syncthreads();
        const float* xr = xs + ln * XSTRIDE + wv * 8;
        const float4 a0 = *(const float4*)(xr);
        const float4 a1 = *(const float4*)(xr + 4);
        xv[c][0] = a0.x; xv[c][1] = a0.y; xv[c][2] = a0.z; xv[c][3] = a0.w;
        xv[c][4] = a1.x; xv[c][5] = a1.y; xv[c][6] = a1.z; xv[c][7] = a1.w;
    }

    float acc[4] = {0.f, 0.f, 0.f, 0.f};
    #pragma unroll 2
    for (int k = 0; k < KDIM; k++) {
        const float* pk = prm + (wv * 8 + k) * PSTRIDE;
        const float cst = pk[44];
        float ee[4] = {cst, cst, cst, cst};
        #pragma unroll
        for (int i = 0; i < 8; i++) {
            const int o = 9 * i - (i * (i - 1)) / 2;
            const float lin = pk[o];
            float inner[4] = {lin, lin, lin, lin};
            #pragma unroll
            for (int j = i; j < 8; j++) {
                const float cf = pk[o + 1 + j - i];
                #pragma unroll
                for (int c = 0; c < 4; c++) inner[c] = fmaf(cf, xv[c][j], inner[c]);
            }
            #pragma unroll
            for (int c = 0; c < 4; c++) ee[c] = fmaf(xv[c][i], inner[c], ee[c]);
        }
        #pragma unroll
        for (int c = 0; c < 4; c++) acc[c] += FAST_EXP2(-ee[c]);
    }

    __syncthreads();
    #pragma unroll
    for (int c = 0; c < 4; c++)
        xs[(c * 64 + ln) * 9 + wv] = acc[c];
    __syncthreads();
    {
        const int row  = tidx >> 1;
        const int part = tidx & 1;
        float4 v;
        v.x = xs[row * 9 + part * 4 + 0];
        v.y = xs[row * 9 + part * 4 + 1];
        v.z = xs[row * 9 + part * 4 + 2];
        v.w = xs[row * 9 + part * 4 + 3];
        *(float4*)(out + (size_t)(b0 + row) * TDIM + t0 + part * 4) = v;
    }
}

extern "C" void kernel_launch(void* const* d_in, const int* in_sizes, int n_in,
                              void* d_out, int out_size, void* d_ws, size_t ws_size,
                              hipStream_t stream) {
    const float* x       = (const float*)d_in[0];  // [2048,512,8]
    const float* centers = (const float*)d_in[1];  // [512,8,8]
    const float* wlogits = (const float*)d_in[2];  // [512,8]
    const float* logvar  = (const float*)d_in[3];  // [512,8,8]
    const float* covp    = (const float*)d_in[4];  // [512,8,28]
    float* out = (float*)d_out;                    // [2048,512]

    if (d_ws != nullptr && ws_size >= (size_t)COEF_BYTES) {
        float* coef = (float*)d_ws;
        // Phase A once: 256 blocks x 128 thr (2 t per block)
        pecd_coef<<<dim3(TDIM / 2), dim3(128), 0, stream>>>(
            centers, wlogits, logvar, covp, coef);
        // Phase B: full occupancy (32 waves/CU), scalar-pipe coef reads
        pecd_main<<<dim3(TDIM / 8, BDIM / 128), dim3(512), 0, stream>>>(x, coef, out);
    } else {
        // fallback: original fused path
        pecd_fused<<<dim3(TDIM / 8, BDIM / 256), dim3(512), 0, stream>>>(
            x, centers, wlogits, logvar, covp, out);
    }
}

// Round 3
// 93.557 us; speedup vs baseline: 1.0171x; 1.0171x over previous
//
#include <hip/hip_runtime.h>
#include <math.h>

#define TDIM 512
#define KDIM 8
#define DDIM 8
#define BDIM 2048

#define PSTRIDE 48   // per tk: 8 i-blocks [lin_i, S'_ii, 2S'_ij...] (44), const@44, pad3
#define XSTRIDE 68   // x staging row stride (fallback kernel only)

#define COEF_FLOATS (TDIM * KDIM * PSTRIDE)   // 4096 * 48 = 196608
#define COEF_BYTES  (COEF_FLOATS * 4)         // 786432

#ifndef __has_builtin
#define __has_builtin(x) 0
#endif
#if __has_builtin(__builtin_amdgcn_exp2f)
#define FAST_EXP2(x) __builtin_amdgcn_exp2f(x)
#else
#define FAST_EXP2(x) exp2f(x)
#endif

// ---------------------------------------------------------------------------
// Kernel 1: coefficient builder (Phase A), run ONCE over T*K.
// 256 blocks x 128 thr: each block = 2 t (16 tk x 8 rows).
// 8-lane-parallel f32 Gauss-Jordan Cayley, then S = Q diag(0.7213*e^-lv) Q^T
// folded into quadratic-form coefs, written to global ws [4096][48].
// ---------------------------------------------------------------------------
__global__ __launch_bounds__(128) void pecd_coef(
    const float* __restrict__ centers,   // [T,K,8]
    const float* __restrict__ wlogits,   // [T,K]
    const float* __restrict__ logvar,    // [T,K,8]
    const float* __restrict__ covp,      // [T,K,28]
    float* __restrict__ coef)            // [T*K,48] ws
{
    const int tidx = (int)threadIdx.x;
    const int t0   = (int)blockIdx.x * 2;

    const int tk = tidx >> 3;             // 0..15 = (t_local, k)
    const int r  = tidx & 7;
    const size_t tkg = (size_t)(t0 + (tk >> 3)) * 8 + (tk & 7);

    // row r of M = I + A ; A = 0.5*(UT^T - UT), UT strict-upper from
    // flat(n) = v[n] (n<28) | v[55-n] (28<=n<56), n = 8*min+max.
    const float* cb = covp + tkg * 28;
    float row[8];
    #pragma unroll
    for (int j = 0; j < 8; j++) {
        const int lo = (r < j) ? r : j;
        const int hi = (r < j) ? j : r;
        const int n  = 8 * lo + hi;
        const int m  = (r == j) ? 0 : ((n < 28) ? n : 55 - n);
        const float v = cb[m];
        const float a = (r < j) ? -0.5f * v : 0.5f * v;
        row[j] = (r == j) ? 1.0f : a;
    }

    #pragma unroll
    for (int c = 0; c < 8; c++) {
        float prow[8];
        #pragma unroll
        for (int j = 0; j < 8; j++) prow[j] = __shfl(row[j], c, 8);
        const float pinv = 1.0f / prow[c];
        const float f = row[c];
        #pragma unroll
        for (int j = 0; j < 8; j++) {
            if (j == c) {
                row[j] = (r == c) ? pinv : -f * pinv;
            } else {
                const float spiv = prow[j] * pinv;
                row[j] = (r == c) ? spiv : fmaf(-f, spiv, row[j]);
            }
        }
    }
    float qr[8];
    #pragma unroll
    for (int j = 0; j < 8; j++) qr[j] = 2.0f * row[j] - (r == j ? 1.0f : 0.0f);

    const float* lvp = logvar + tkg * 8;
    float sc2[8];
    float sumlv = 0.0f;
    #pragma unroll
    for (int j = 0; j < 8; j++) {
        const float lv = fminf(fmaxf(lvp[j], -3.5f), 3.5f);
        sumlv += lv;
        sc2[j] = 0.7213475204444817f * exp2f(lv * -1.4426950408889634f);
    }
    float w[8];
    #pragma unroll
    for (int j = 0; j < 8; j++) w[j] = qr[j] * sc2[j];

    float Srow[8];
    #pragma unroll
    for (int m = 0; m < 8; m++) {
        float s = 0.0f;
        #pragma unroll
        for (int j = 0; j < 8; j++) s = fmaf(w[j], __shfl(qr[j], m, 8), s);
        Srow[m] = s;
    }

    const float* cp = centers + tkg * 8;
    float tr = 0.0f;
    #pragma unroll
    for (int m = 0; m < 8; m++) tr = fmaf(Srow[m], cp[m], tr);
    const float lin = -2.0f * tr;
    float cpart = cp[r] * tr;
    cpart += __shfl_xor(cpart, 1, 8);
    cpart += __shfl_xor(cpart, 2, 8);
    cpart += __shfl_xor(cpart, 4, 8);   // = c^T S c

    // softmax over k (k = tid bits 3..5, within-wave) -> log2(w)
    float l = fminf(fmaxf(wlogits[tkg], -3.5f), 3.5f);
    float mx = l;
    mx = fmaxf(mx, __shfl_xor(mx, 8, 64));
    mx = fmaxf(mx, __shfl_xor(mx, 16, 64));
    mx = fmaxf(mx, __shfl_xor(mx, 32, 64));
    const float e = exp2f((l - mx) * 1.4426950408889634f);
    float ss = e;
    ss += __shfl_xor(ss, 8, 64);
    ss += __shfl_xor(ss, 16, 64);
    ss += __shfl_xor(ss, 32, 64);
    const float log2w = (l - mx) * 1.4426950408889634f - log2f(ss);
    const float slc = log2w - 10.605984517349169f - 0.7213475204444817f * sumlv;

    float* pp = coef + tkg * PSTRIDE;
    const int o = 9 * r - (r * (r - 1)) / 2;   // 0,9,17,24,30,35,39,42
    pp[o] = lin;
    #pragma unroll
    for (int j = 0; j < 8; j++) {
        if (j >= r) pp[o + 1 + j - r] = Srow[j] * ((j == r) ? 1.0f : 2.0f);
    }
    if (r == 0) pp[44] = cpart - slc;
}

// ---------------------------------------------------------------------------
// Kernel 2: evaluation (Phase B). 2 outputs/thread, grid (64,16) = 1024
// blocks -> 4 blocks/CU x 8 waves = 32 waves/CU (full occupancy).
// wave<->t, lane<->b. x loaded DIRECTLY to registers (no LDS staging, no
// barriers): each 128-B x line is fully consumed by 4 waves of the block
// (wave wv reads floats (t0+wv)*8..+8 of each row), so scattered
// global_load_dwordx4 is line-efficient and L1-served after first touch.
// Coefs are wave-uniform -> readfirstlane-uniform pointer -> s_load into
// SGPRs (scalar pipe runs parallel to VALU). Only remaining LDS: 4.6 KB
// out-transpose buffer with a single barrier.
// ---------------------------------------------------------------------------
__global__ __launch_bounds__(512, 8) void pecd_main(
    const float* __restrict__ x,         // [B,T,8]
    const float* __restrict__ coef,      // [T*K,48] ws
    float* __restrict__ out)             // [B,T]
{
    __shared__ float xs[128 * 9];        // 4.6 KB transpose buffer

    const int tidx = (int)threadIdx.x;
    const int t0   = (int)blockIdx.x * 8;     // wave w handles t0+w
    const int b0   = (int)blockIdx.y * 128;   // 2 chunks of 64 b

    const int wv = tidx >> 6;
    const int ln = tidx & 63;

    // direct x loads: 8 floats per chunk, per lane (2x global_load_dwordx4)
    float xv[2][8];
    #pragma unroll
    for (int c = 0; c < 2; c++) {
        const float* xp = x + ((size_t)(b0 + c * 64 + ln) * TDIM + (t0 + wv)) * DDIM;
        const float4 a0 = *(const float4*)(xp);
        const float4 a1 = *(const float4*)(xp + 4);
        xv[c][0] = a0.x; xv[c][1] = a0.y; xv[c][2] = a0.z; xv[c][3] = a0.w;
        xv[c][4] = a1.x; xv[c][5] = a1.y; xv[c][6] = a1.z; xv[c][7] = a1.w;
    }

    // wave-uniform coef base -> scalar loads (s_load) from L2-resident ws
    const int wvu = __builtin_amdgcn_readfirstlane(wv);
    const float* __restrict__ pkb = coef + (size_t)(t0 + wvu) * (KDIM * PSTRIDE);

    float acc[2] = {0.f, 0.f};
    #pragma unroll 2
    for (int k = 0; k < KDIM; k++) {
        const float* __restrict__ pk = pkb + k * PSTRIDE;  // uniform address
        const float cst = pk[44];
        float ee[2] = {cst, cst};
        #pragma unroll
        for (int i = 0; i < 8; i++) {
            const int o = 9 * i - (i * (i - 1)) / 2;
            const float lin = pk[o];
            float inner[2] = {lin, lin};
            #pragma unroll
            for (int j = i; j < 8; j++) {
                const float cf = pk[o + 1 + j - i];
                #pragma unroll
                for (int c = 0; c < 2; c++) inner[c] = fmaf(cf, xv[c][j], inner[c]);
            }
            #pragma unroll
            for (int c = 0; c < 2; c++) ee[c] = fmaf(xv[c][i], inner[c], ee[c]);
        }
        #pragma unroll
        for (int c = 0; c < 2; c++) acc[c] += FAST_EXP2(-ee[c]);
    }

    // ---- transpose through LDS (128 rows x 9 = 4.6 KB), single barrier ----
    #pragma unroll
    for (int c = 0; c < 2; c++)
        xs[(c * 64 + ln) * 9 + wv] = acc[c];   // stride 9: conflict-free
    __syncthreads();
    if (tidx < 256) {
        const int row  = tidx >> 1;    // 0..127 local b
        const int part = tidx & 1;     // float4 half of the 8-t row
        float4 v;
        v.x = xs[row * 9 + part * 4 + 0];
        v.y = xs[row * 9 + part * 4 + 1];
        v.z = xs[row * 9 + part * 4 + 2];
        v.w = xs[row * 9 + part * 4 + 3];
        *(float4*)(out + (size_t)(b0 + row) * TDIM + t0 + part * 4) = v;
    }
}

// ---------------------------------------------------------------------------
// Fallback: original fused single-kernel path (used if ws too small).
// ---------------------------------------------------------------------------
__global__ __launch_bounds__(512, 4) void pecd_fused(
    const float* __restrict__ x,
    const float* __restrict__ centers,
    const float* __restrict__ wlogits,
    const float* __restrict__ logvar,
    const float* __restrict__ covp,
    float* __restrict__ out)
{
    __shared__ float prm[64 * PSTRIDE];
    __shared__ float xs[64 * XSTRIDE];

    const int tidx = (int)threadIdx.x;
    const int t0   = (int)blockIdx.x * 8;
    const int b0   = (int)blockIdx.y * 256;

    {
        const int tk = tidx >> 3;
        const int r  = tidx & 7;
        const size_t tkg = (size_t)(t0 + (tk >> 3)) * 8 + (tk & 7);

        const float* cb = covp + tkg * 28;
        float row[8];
        #pragma unroll
        for (int j = 0; j < 8; j++) {
            const int lo = (r < j) ? r : j;
            const int hi = (r < j) ? j : r;
            const int n  = 8 * lo + hi;
            const int m  = (r == j) ? 0 : ((n < 28) ? n : 55 - n);
            const float v = cb[m];
            const float a = (r < j) ? -0.5f * v : 0.5f * v;
            row[j] = (r == j) ? 1.0f : a;
        }

        #pragma unroll
        for (int c = 0; c < 8; c++) {
            float prow[8];
            #pragma unroll
            for (int j = 0; j < 8; j++) prow[j] = __shfl(row[j], c, 8);
            const float pinv = 1.0f / prow[c];
            const float f = row[c];
            #pragma unroll
            for (int j = 0; j < 8; j++) {
                if (j == c) {
                    row[j] = (r == c) ? pinv : -f * pinv;
                } else {
                    const float spiv = prow[j] * pinv;
                    row[j] = (r == c) ? spiv : fmaf(-f, spiv, row[j]);
                }
            }
        }
        float qr[8];
        #pragma unroll
        for (int j = 0; j < 8; j++) qr[j] = 2.0f * row[j] - (r == j ? 1.0f : 0.0f);

        const float* lvp = logvar + tkg * 8;
        float sc2[8];
        float sumlv = 0.0f;
        #pragma unroll
        for (int j = 0; j < 8; j++) {
            const float lv = fminf(fmaxf(lvp[j], -3.5f), 3.5f);
            sumlv += lv;
            sc2[j] = 0.7213475204444817f * exp2f(lv * -1.4426950408889634f);
        }
        float w[8];
        #pragma unroll
        for (int j = 0; j < 8; j++) w[j] = qr[j] * sc2[j];

        float Srow[8];
        #pragma unroll
        for (int m = 0; m < 8; m++) {
            float s = 0.0f;
            #pragma unroll
            for (int j = 0; j < 8; j++) s = fmaf(w[j], __shfl(qr[j], m, 8), s);
            Srow[m] = s;
        }

        const float* cp = centers + tkg * 8;
        float tr = 0.0f;
        #pragma unroll
        for (int m = 0; m < 8; m++) tr = fmaf(Srow[m], cp[m], tr);
        const float lin = -2.0f * tr;
        float cpart = cp[r] * tr;
        cpart += __shfl_xor(cpart, 1, 8);
        cpart += __shfl_xor(cpart, 2, 8);
        cpart += __shfl_xor(cpart, 4, 8);

        float l = fminf(fmaxf(wlogits[tkg], -3.5f), 3.5f);
        float mx = l;
        mx = fmaxf(mx, __shfl_xor(mx, 8, 64));
        mx = fmaxf(mx, __shfl_xor(mx, 16, 64));
        mx = fmaxf(mx, __shfl_xor(mx, 32, 64));
        const float e = exp2f((l - mx) * 1.4426950408889634f);
        float ss = e;
        ss += __shfl_xor(ss, 8, 64);
        ss += __shfl_xor(ss, 16, 64);
        ss += __shfl_xor(ss, 32, 64);
        const float log2w = (l - mx) * 1.4426950408889634f - log2f(ss);
        const float slc = log2w - 10.605984517349169f - 0.7213475204444817f * sumlv;

        float* pp = prm + tk * PSTRIDE;
        const int o = 9 * r - (r * (r - 1)) / 2;
        pp[o] = lin;
        #pragma unroll
        for (int j = 0; j < 8; j++) {
            if (j >= r) pp[o + 1 + j - r] = Srow[j] * ((j == r) ? 1.0f : 2.0f);
        }
        if (r == 0) pp[44] = cpart - slc;
    }

    const int wv = tidx >> 6;
    const int ln = tidx & 63;

    float xv[4][8];
    #pragma unroll
    for (int c = 0; c < 4; c++) {
        __syncthreads();
        #pragma unroll
        for (int it = 0; it < 2; it++) {
            const int idx = tidx + it * 512;
            const int row = idx >> 4;
            const int col = idx & 15;
            const float4 v =
                *((const float4*)(x + ((size_t)(b0 + c * 64 + row) * TDIM + t0) * DDIM) + col);
            *(float4*)(xs + row * XSTRIDE + col * 4) = v;
        }
        __syncthreads();
        const float* xr = xs + ln * XSTRIDE + wv * 8;
        const float4 a0 = *(const float4*)(xr);
        const float4 a1 = *(const float4*)(xr + 4);
        xv[c][0] = a0.x; xv[c][1] = a0.y; xv[c][2] = a0.z; xv[c][3] = a0.w;
        xv[c][4] = a1.x; xv[c][5] = a1.y; xv[c][6] = a1.z; xv[c][7] = a1.w;
    }

    float acc[4] = {0.f, 0.f, 0.f, 0.f};
    #pragma unroll 2
    for (int k = 0; k < KDIM; k++) {
        const float* pk = prm + (wv * 8 + k) * PSTRIDE;
        const float cst = pk[44];
        float ee[4] = {cst, cst, cst, cst};
        #pragma unroll
        for (int i = 0; i < 8; i++) {
            const int o = 9 * i - (i * (i - 1)) / 2;
            const float lin = pk[o];
            float inner[4] = {lin, lin, lin, lin};
            #pragma unroll
            for (int j = i; j < 8; j++) {
                const float cf = pk[o + 1 + j - i];
                #pragma unroll
                for (int c = 0; c < 4; c++) inner[c] = fmaf(cf, xv[c][j], inner[c]);
            }
            #pragma unroll
            for (int c = 0; c < 4; c++) ee[c] = fmaf(xv[c][i], inner[c], ee[c]);
        }
        #pragma unroll
        for (int c = 0; c < 4; c++) acc[c] += FAST_EXP2(-ee[c]);
    }

    __syncthreads();
    #pragma unroll
    for (int c = 0; c < 4; c++)
        xs[(c * 64 + ln) * 9 + wv] = acc[c];
    __syncthreads();
    {
        const int row  = tidx >> 1;
        const int part = tidx & 1;
        float4 v;
        v.x = xs[row * 9 + part * 4 + 0];
        v.y = xs[row * 9 + part * 4 + 1];
        v.z = xs[row * 9 + part * 4 + 2];
        v.w = xs[row * 9 + part * 4 + 3];
        *(float4*)(out + (size_t)(b0 + row) * TDIM + t0 + part * 4) = v;
    }
}

extern "C" void kernel_launch(void* const* d_in, const int* in_sizes, int n_in,
                              void* d_out, int out_size, void* d_ws, size_t ws_size,
                              hipStream_t stream) {
    const float* x       = (const float*)d_in[0];  // [2048,512,8]
    const float* centers = (const float*)d_in[1];  // [512,8,8]
    const float* wlogits = (const float*)d_in[2];  // [512,8]
    const float* logvar  = (const float*)d_in[3];  // [512,8,8]
    const float* covp    = (const float*)d_in[4];  // [512,8,28]
    float* out = (float*)d_out;                    // [2048,512]

    if (d_ws != nullptr && ws_size >= (size_t)COEF_BYTES) {
        float* coef = (float*)d_ws;
        // Phase A once: 256 blocks x 128 thr (2 t per block)
        pecd_coef<<<dim3(TDIM / 2), dim3(128), 0, stream>>>(
            centers, wlogits, logvar, covp, coef);
        // Phase B: full occupancy (32 waves/CU), barrier-free streaming
        pecd_main<<<dim3(TDIM / 8, BDIM / 128), dim3(512), 0, stream>>>(x, coef, out);
    } else {
        // fallback: original fused path
        pecd_fused<<<dim3(TDIM / 8, BDIM / 256), dim3(512), 0, stream>>>(
            x, centers, wlogits, logvar, covp, out);
    }
}